// Round 12
// baseline (382.540 us; speedup 1.0000x reference)
//
#include <hip/hip_runtime.h>
#include <math.h>

// Workspace float offsets
#define OFF_A      0u          // A (16,2048,256) fp32          8388608
#define OFF_P      8388608u    // cc1 partials [8][16][256][64] 2097152
#define OFF_WCC1   10485760u   // [c2048][oc64][4]               524288
#define OFF_BCC1   11010048u   // 64
#define OFF_WCC2   11010112u   // [ic64][oc64][4]                 16384
#define OFF_BCC2   11026496u   // 64
#define OFF_WRD1   11026560u   // [ic64][oc128][4]                32768
#define OFF_BRD1   11059328u   // 128
#define OFF_WRD2   11059456u   // [ic128][oc128][4]               65536
#define OFF_BRD2   11124992u   // 128
#define OFF_WUP1   11125120u   // [v3][ic128][oc64][4]            98304
#define OFF_BUP1   11223424u   // 64
#define OFF_WUP2   11223488u   // [v5][src3][ic64][oc32][4]      122880
#define OFF_BUP2   11346368u   // 32
#define OFF_WRX    11346400u   // folded rx weights [rxi][ic32][oc32] 4096
#define OFF_W1F    11350496u   // folded tc1 [oc16][6]                96
#define OFF_B1F    11350592u   // 16
#define OFF_W2F    11350608u   // folded tc2 [ic16][k3][oc32]       1536
#define OFF_B2F    11352144u   // 32
#define OFF_BRXF   11352176u   // 32
#define OFF_S01    11352208u   // wd column sums c=2..61 [2][64]     128
// Aliased over A (A dead after k_cc1):
#define OFF_RP0    0u          // rd2 partial half0 [16][256][128] 524288
#define OFF_RP1    524288u     // rd2 partial half1                524288
#define OFF_H      1048576u    // H [16][5][256]                    20480
// total ws floats 11352336 (~43.3 MiB)

__device__ __forceinline__ void fma4(float4& a, const float4& x, float w) {
  a.x = fmaf(x.x, w, a.x); a.y = fmaf(x.y, w, a.y);
  a.z = fmaf(x.z, w, a.z); a.w = fmaf(x.w, w, a.w);
}

// ------------------------------------------- tiny front-weight repack -------
__global__ __launch_bounds__(256) void k_repack_front(
    const float* __restrict__ tc1_w, const float* __restrict__ tc1_b, const float* __restrict__ tc1_s, const float* __restrict__ tc1_t,
    const float* __restrict__ tc2_w, const float* __restrict__ tc2_b, const float* __restrict__ tc2_s, const float* __restrict__ tc2_t,
    const float* __restrict__ rx_w, const float* __restrict__ rx_b, const float* __restrict__ rx_s, const float* __restrict__ rx_t,
    const float* __restrict__ wd,
    float* __restrict__ ws)
{
  const int tid = blockIdx.x * blockDim.x + threadIdx.x;
  const int nth = gridDim.x * blockDim.x;
  for (int i = tid; i < 96; i += nth) ws[OFF_W1F + i] = tc1_w[i] * tc1_s[i/6];
  for (int i = tid; i < 16; i += nth) ws[OFF_B1F + i] = tc1_b[i]*tc1_s[i] + tc1_t[i];
  for (int i = tid; i < 1536; i += nth) {
    int oc = i & 31, r = i >> 5, k = r % 3, ic = r / 3;
    ws[OFF_W2F + i] = tc2_w[oc*48 + ic*3 + k] * tc2_s[oc];
  }
  for (int i = tid; i < 32; i += nth) ws[OFF_B2F + i] = tc2_b[i]*tc2_s[i] + tc2_t[i];
  for (int i = tid; i < 4096; i += nth) {
    int oc = i & 31, ic = (i >> 5) & 31, rxi = i >> 10;
    ws[OFF_WRX + i] = rx_w[(oc*32 + ic)*4 + rxi] * rx_s[oc];
  }
  for (int i = tid; i < 32; i += nth) ws[OFF_BRXF + i] = rx_b[i]*rx_s[i] + rx_t[i];
  // wd column sums for chirp rows 2..61 (the 60 identical middle h-rows)
  for (int i = tid; i < 128; i += nth) {
    int d = i & 63, comp = i >> 6;
    float a = 0.f;
    for (int c = 2; c <= 61; ++c) a += wd[(c*64 + d)*2 + comp];
    ws[OFF_S01 + comp*64 + d] = a;
  }
}

// ---------------------- fused tc1+tc2+rx  +  heavy weight repack ------------
__global__ __launch_bounds__(256, 4) void k_front(
    const float* __restrict__ x, const float* __restrict__ ws_c, float* __restrict__ ws,
    const float* __restrict__ cc1_w, const float* __restrict__ cc1_b, const float* __restrict__ cc1_s, const float* __restrict__ cc1_t,
    const float* __restrict__ cc2_w, const float* __restrict__ cc2_b, const float* __restrict__ cc2_s, const float* __restrict__ cc2_t,
    const float* __restrict__ rd1_w, const float* __restrict__ rd1_b, const float* __restrict__ rd1_s, const float* __restrict__ rd1_t,
    const float* __restrict__ rd2_w, const float* __restrict__ rd2_b, const float* __restrict__ rd2_s, const float* __restrict__ rd2_t,
    const float* __restrict__ up1_w, const float* __restrict__ up1_b, const float* __restrict__ up1_s, const float* __restrict__ up1_t,
    const float* __restrict__ up2_w, const float* __restrict__ up2_b, const float* __restrict__ up2_s, const float* __restrict__ up2_t,
    float* __restrict__ A)
{
  __shared__ float t1s[16][258];
  const int tid = threadIdx.x;

  if (blockIdx.x < 64) {
    const int t = blockIdx.x * 256 + tid;
    const int nth = 64 * 256;
    for (int i = t; i < 2048*64*4; i += nth) {
      int k = i & 3, oc = (i >> 2) & 63, c2 = i >> 8;
      ws[OFF_WCC1 + i] = (k < 3) ? cc1_w[((oc*2048 + c2)*3 + 1)*3 + k] * cc1_s[oc] : 0.f;
    }
    for (int i = t; i < 64; i += nth) ws[OFF_BCC1 + i] = cc1_b[i]*cc1_s[i] + cc1_t[i];
    for (int i = t; i < 64*64; i += nth) {
      int oc = i & 63, ic = i >> 6;
      float4 v;
      v.x = cc2_w[(oc*64 + ic)*9 + 3] * cc2_s[oc];
      v.y = cc2_w[(oc*64 + ic)*9 + 4] * cc2_s[oc];
      v.z = cc2_w[(oc*64 + ic)*9 + 5] * cc2_s[oc];
      v.w = 0.f;
      ((float4*)(ws + OFF_WCC2))[i] = v;
    }
    for (int i = t; i < 64; i += nth) ws[OFF_BCC2 + i] = cc2_b[i]*cc2_s[i] + cc2_t[i];
    for (int i = t; i < 64*128; i += nth) {
      int oc = i & 127, ic = i >> 7;
      float4 v;
      v.x = rd1_w[(oc*64 + ic)*9 + 3] * rd1_s[oc];
      v.y = rd1_w[(oc*64 + ic)*9 + 4] * rd1_s[oc];
      v.z = rd1_w[(oc*64 + ic)*9 + 5] * rd1_s[oc];
      v.w = 0.f;
      ((float4*)(ws + OFF_WRD1))[i] = v;
    }
    for (int i = t; i < 128; i += nth) ws[OFF_BRD1 + i] = rd1_b[i]*rd1_s[i] + rd1_t[i];
    for (int i = t; i < 128*128; i += nth) {
      int oc = i & 127, ic = i >> 7;
      float4 v;
      v.x = rd2_w[(oc*128 + ic)*9 + 3] * rd2_s[oc];
      v.y = rd2_w[(oc*128 + ic)*9 + 4] * rd2_s[oc];
      v.z = rd2_w[(oc*128 + ic)*9 + 5] * rd2_s[oc];
      v.w = 0.f;
      ((float4*)(ws + OFF_WRD2))[i] = v;
    }
    for (int i = t; i < 128; i += nth) ws[OFF_BRD2 + i] = rd2_b[i]*rd2_s[i] + rd2_t[i];
    for (int i = t; i < 3*128*64; i += nth) {
      int oc = i & 63, ic = (i >> 6) & 127, v = i >> 13;
      const int m = (v == 0) ? 6 : (v == 1) ? 7 : 3;
      float4 o = make_float4(0.f, 0.f, 0.f, 0.f);
      for (int kh = 0; kh < 3; ++kh)
        if ((m >> kh) & 1) {
          o.x += up1_w[((oc*128 + ic)*3 + kh)*3 + 0];
          o.y += up1_w[((oc*128 + ic)*3 + kh)*3 + 1];
          o.z += up1_w[((oc*128 + ic)*3 + kh)*3 + 2];
        }
      o.x *= up1_s[oc]; o.y *= up1_s[oc]; o.z *= up1_s[oc];
      ((float4*)(ws + OFF_WUP1))[i] = o;
    }
    for (int i = t; i < 64; i += nth) ws[OFF_BUP1 + i] = up1_b[i]*up1_s[i] + up1_t[i];
    for (int i = t; i < 5*3*64*32; i += nth) {
      int oc = i & 31, ic = (i >> 5) & 63, tt = i >> 11;
      int src = tt % 3, v = tt / 3;
      const int MASKS[15] = {2,4,0,  1,6,0,  0,7,0,  0,3,4,  0,1,2};
      const int m = MASKS[v*3 + src];
      float4 o = make_float4(0.f, 0.f, 0.f, 0.f);
      for (int kh = 0; kh < 3; ++kh)
        if ((m >> kh) & 1) {
          o.x += up2_w[((oc*64 + ic)*3 + kh)*3 + 0];
          o.y += up2_w[((oc*64 + ic)*3 + kh)*3 + 1];
          o.z += up2_w[((oc*64 + ic)*3 + kh)*3 + 2];
        }
      o.x *= up2_s[oc]; o.y *= up2_s[oc]; o.z *= up2_s[oc];
      ((float4*)(ws + OFF_WUP2))[i] = o;
    }
    for (int i = t; i < 32; i += nth) ws[OFF_BUP2 + i] = up2_b[i]*up2_s[i] + up2_t[i];
    return;
  }

  // ---------------------------- front compute -------------------------------
  const int bb = blockIdx.x - 64;
  const int b = bb >> 6, chirp = bb & 63;
  const int s = tid;

  if (tid < 32) { int o = tid & 15; int c = (tid >> 4) ? 257 : 0; t1s[o][c] = 0.f; }

  const float* w1f  = ws_c + OFF_W1F;
  const float* b1f  = ws_c + OFF_B1F;
  const float* w2f  = ws_c + OFF_W2F;
  const float* b2f  = ws_c + OFF_B2F;
  const float* wrxf = ws_c + OFF_WRX;
  const float* brxf = ws_c + OFF_BRXF;

  float acc[32];
  #pragma unroll
  for (int j = 0; j < 32; ++j) acc[j] = 0.f;

  #pragma unroll 1
  for (int rxi = 0; rxi < 4; ++rxi) {
    {
      const float2* xb2 = (const float2*)(x + ((size_t)(((b*4 + rxi)*64 + chirp)*256) << 1));
      float2 xm = xb2[s];
      float2 xl = xb2[(s == 0) ? 0 : (s - 1)];
      float2 xr = xb2[(s == 255) ? 255 : (s + 1)];
      if (s == 0)   { xl.x = 0.f; xl.y = 0.f; }
      if (s == 255) { xr.x = 0.f; xr.y = 0.f; }
      #pragma unroll 4
      for (int o = 0; o < 16; ++o) {
        const float* w = w1f + o*6;
        float v = b1f[o];
        v = fmaf(xl.x, w[0], v);
        v = fmaf(xm.x, w[1], v);
        v = fmaf(xr.x, w[2], v);
        v = fmaf(xl.y, w[3], v);
        v = fmaf(xm.y, w[4], v);
        v = fmaf(xr.y, w[5], v);
        t1s[o][s+1] = fmaxf(v, 0.f);
      }
    }
    __syncthreads();

    float t2[32];
    #pragma unroll
    for (int j = 0; j < 32; ++j) t2[j] = b2f[j];
    #pragma unroll 2
    for (int ic = 0; ic < 16; ++ic) {
      float tl = t1s[ic][s];
      float tm = t1s[ic][s+1];
      float tr = t1s[ic][s+2];
      const float* w = w2f + ic*96;
      #pragma unroll
      for (int oc = 0; oc < 32; ++oc)
        t2[oc] = fmaf(tl, w[oc], fmaf(tm, w[32+oc], fmaf(tr, w[64+oc], t2[oc])));
    }
    #pragma unroll
    for (int j = 0; j < 32; ++j) t2[j] = fmaxf(t2[j], 0.f);

    const float* wr0 = wrxf + rxi*1024;
    #pragma unroll 4
    for (int ic = 0; ic < 32; ++ic) {
      float tv = t2[ic];
      const float* w = wr0 + ic*32;
      #pragma unroll
      for (int oc = 0; oc < 32; ++oc)
        acc[oc] = fmaf(tv, w[oc], acc[oc]);
    }
    __syncthreads();
  }

  #pragma unroll 4
  for (int oc = 0; oc < 32; ++oc) {
    float v = fmaxf(acc[oc] + brxf[oc], 0.f);
    A[(size_t)((b*2048 + oc*64 + chirp)*256) + s] = v;
  }
}

// --------------------------------------------------------- cc1 (split-K8) ---
// 2048 blocks (16b x 16st(16 samples) x 8ks), 256 thr = (oc64 x sg4),
// 4 samples/thread. LDS 20 KB -> 8 blocks/CU = 32 waves/CU.
// Per c: 1 coalesced VMEM float4 + 2 broadcast LDS + 12 FMA.
__global__ __launch_bounds__(256, 8) void k_cc1(
    const float* __restrict__ A, const float* __restrict__ wp, float* __restrict__ P)
{
  __shared__ __align__(16) float As[256][20];   // si 0..17 <-> sA s0-1..s0+16
  const int tid = threadIdx.x;
  const int ks = blockIdx.x & 7;
  const int stile = (blockIdx.x >> 3) & 15;
  const int b = blockIdx.x >> 7;
  const int s0 = stile * 16;
  const int oc = tid & 63;
  const int sg = tid >> 6;
  const int cbase = ks * 256;
  const float4* w4 = (const float4*)wp;

  for (int i = tid; i < 256*20; i += 256) {
    int c = i / 20, si = i - c*20;
    int sA = s0 - 1 + si;
    float v = 0.f;
    if (si < 18 && sA >= 0 && sA < 256)
      v = A[(size_t)(b*2048 + cbase + c)*256 + sA];
    As[c][si] = v;
  }
  __syncthreads();

  const int sb = sg * 4;
  float4 acc = make_float4(0.f,0.f,0.f,0.f);
  #pragma unroll 8
  for (int c = 0; c < 256; ++c) {
    float4 w = w4[(size_t)(cbase + c)*64 + oc];
    float4 a0 = *(const float4*)&As[c][sb];
    float2 a1 = *(const float2*)&As[c][sb + 4];
    acc.x = fmaf(a0.x,w.x, fmaf(a0.y,w.y, fmaf(a0.z,w.z, acc.x)));
    acc.y = fmaf(a0.y,w.x, fmaf(a0.z,w.y, fmaf(a0.w,w.z, acc.y)));
    acc.z = fmaf(a0.z,w.x, fmaf(a0.w,w.y, fmaf(a1.x,w.z, acc.z)));
    acc.w = fmaf(a0.w,w.x, fmaf(a1.x,w.y, fmaf(a1.y,w.z, acc.w)));
  }
  float* Pk = P + ((size_t)(ks*16 + b)*256)*64;
  int s = s0 + sb;
  Pk[(size_t)(s+0)*64 + oc] = acc.x;
  Pk[(size_t)(s+1)*64 + oc] = acc.y;
  Pk[(size_t)(s+2)*64 + oc] = acc.z;
  Pk[(size_t)(s+3)*64 + oc] = acc.w;
}

// ------------------- fused cc2 + rd1 + rd2 (oc-half split) ------------------
__global__ __launch_bounds__(256) void k_mid(
    const float* __restrict__ P, const float* __restrict__ bcc1,
    const float* __restrict__ wcc2, const float* __restrict__ bcc2,
    const float* __restrict__ wrd1, const float* __restrict__ brd1,
    const float* __restrict__ wrd2, const float* __restrict__ brd2,
    float* __restrict__ Rp0, float* __restrict__ Rp1)
{
  __shared__ __align__(16) float c1s[64][20];  // si 0..13 <-> sA s0-3..s0+10
  __shared__ __align__(16) float c2s[64][20];  // si 0..11 <-> sA s0-2..s0+9; 12,13 zero
  __shared__ __align__(16) float r1s[64][12];  // si 0..9  <-> sA s0-1..s0+8; 10,11 zero
  const int tid = threadIdx.x;
  const int half = blockIdx.x & 1;
  const int stile = (blockIdx.x >> 1) & 31;
  const int b = blockIdx.x >> 6;
  const int s0 = stile * 8;
  const float4* wc2 = (const float4*)wcc2;
  const float4* wr1 = (const float4*)wrd1;
  const float4* wr2 = (const float4*)wrd2;

  for (int i = tid; i < 14*64; i += 256) {
    int ic = i & 63, si = i >> 6;
    int sA = s0 - 3 + si;
    float v = 0.f;
    if (sA >= 0 && sA < 256) {
      float a = bcc1[ic];
      #pragma unroll
      for (int ksp = 0; ksp < 8; ++ksp)
        a += P[((size_t)(ksp*16 + b)*256 + sA)*64 + ic];
      v = fmaxf(a, 0.f);
    }
    c1s[ic][si] = v;
  }
  __syncthreads();

  {
    const int g = tid >> 6, oc = tid & 63;
    if (g < 3) {
      float bb = bcc2[oc];
      float4 acc = make_float4(bb, bb, bb, bb);
      #pragma unroll 4
      for (int ic = 0; ic < 64; ++ic) {
        float4 w = wc2[ic*64 + oc];
        float4 ca = *(const float4*)&c1s[ic][g*4];
        float2 cb = *(const float2*)&c1s[ic][g*4 + 4];
        acc.x = fmaf(ca.x,w.x, fmaf(ca.y,w.y, fmaf(ca.z,w.z, acc.x)));
        acc.y = fmaf(ca.y,w.x, fmaf(ca.z,w.y, fmaf(ca.w,w.z, acc.y)));
        acc.z = fmaf(ca.z,w.x, fmaf(ca.w,w.y, fmaf(cb.x,w.z, acc.z)));
        acc.w = fmaf(ca.w,w.x, fmaf(cb.x,w.y, fmaf(cb.y,w.z, acc.w)));
      }
      float r[4] = {acc.x, acc.y, acc.z, acc.w};
      #pragma unroll
      for (int j = 0; j < 4; ++j) {
        int si = g*4 + j, sA = s0 - 2 + si;
        c2s[oc][si] = (sA >= 0 && sA < 256) ? fmaxf(r[j], 0.f) : 0.f;
      }
    } else {
      int oc2 = tid - 192;
      c2s[oc2][12] = 0.f;
      c2s[oc2][13] = 0.f;
    }
  }
  __syncthreads();

  {
    const int g = tid >> 6, ocl = tid & 63;
    if (g < 3) {
      const int ocg = half*64 + ocl;
      float bb = brd1[ocg];
      float4 acc = make_float4(bb, bb, bb, bb);
      #pragma unroll 4
      for (int ic = 0; ic < 64; ++ic) {
        float4 w = wr1[ic*128 + ocg];
        float4 ca = *(const float4*)&c2s[ic][g*4];
        float2 cb = *(const float2*)&c2s[ic][g*4 + 4];
        acc.x = fmaf(ca.x,w.x, fmaf(ca.y,w.y, fmaf(ca.z,w.z, acc.x)));
        acc.y = fmaf(ca.y,w.x, fmaf(ca.z,w.y, fmaf(ca.w,w.z, acc.y)));
        acc.z = fmaf(ca.z,w.x, fmaf(ca.w,w.y, fmaf(cb.x,w.z, acc.z)));
        acc.w = fmaf(ca.w,w.x, fmaf(cb.x,w.y, fmaf(cb.y,w.z, acc.w)));
      }
      float r[4] = {acc.x, acc.y, acc.z, acc.w};
      #pragma unroll
      for (int j = 0; j < 4; ++j) {
        int si = g*4 + j, sA = s0 - 1 + si;
        if (si < 10)
          r1s[ocl][si] = (sA >= 0 && sA < 256) ? fmaxf(r[j], 0.f) : 0.f;
      }
    } else {
      int oc2 = tid - 192;
      r1s[oc2][10] = 0.f;
      r1s[oc2][11] = 0.f;
    }
  }
  __syncthreads();

  {
    const int g = tid >> 7, oc = tid & 127;
    float bb = half ? 0.f : brd2[oc];
    float4 acc = make_float4(bb, bb, bb, bb);
    #pragma unroll 4
    for (int ic = 0; ic < 64; ++ic) {
      float4 w = wr2[(half*64 + ic)*128 + oc];
      float4 ca = *(const float4*)&r1s[ic][g*4];
      float2 cb = *(const float2*)&r1s[ic][g*4 + 4];
      acc.x = fmaf(ca.x,w.x, fmaf(ca.y,w.y, fmaf(ca.z,w.z, acc.x)));
      acc.y = fmaf(ca.y,w.x, fmaf(ca.z,w.y, fmaf(ca.w,w.z, acc.y)));
      acc.z = fmaf(ca.z,w.x, fmaf(ca.w,w.y, fmaf(cb.x,w.z, acc.z)));
      acc.w = fmaf(ca.w,w.x, fmaf(cb.x,w.y, fmaf(cb.y,w.z, acc.w)));
    }
    float* Rp = half ? Rp1 : Rp0;
    int s = s0 + g*4;
    Rp[((size_t)b*256 + s+0)*128 + oc] = acc.x;
    Rp[((size_t)b*256 + s+1)*128 + oc] = acc.y;
    Rp[((size_t)b*256 + s+2)*128 + oc] = acc.z;
    Rp[((size_t)b*256 + s+3)*128 + oc] = acc.w;
  }
}

// ------------------------- fused up1 + up2 + up3 + sigmoid ------------------
// 1024 blocks (16b x 64 tiles of 4 samples), 192 thr -> 4 blocks/CU = 12 waves.
__global__ __launch_bounds__(192) void k_up(
    const float* __restrict__ Rp0, const float* __restrict__ Rp1,
    const float* __restrict__ wup1, const float* __restrict__ bup1,
    const float* __restrict__ wup2, const float* __restrict__ bup2,
    const float* __restrict__ up3_w, const float* __restrict__ up3_b,
    float* __restrict__ H)
{
  __shared__ __align__(16) float Rs[128][8];    // si 0..7 <-> sA s0-2..s0+5
  __shared__ __align__(16) float u1s[3][64][8]; // p 0..5 <-> sA s0-1..s0+4; 6,7 zero
  __shared__ float u2s[5][32][5];
  const int tid = threadIdx.x;
  const int b = blockIdx.x >> 6;
  const int s0 = (blockIdx.x & 63) * 4;

  for (int i = tid; i < 128*8; i += 192) {
    int ic = i >> 3, si = i & 7;
    int sA = s0 - 2 + si;
    float v = 0.f;
    if (sA >= 0 && sA < 256) {
      size_t idx = ((size_t)b*256 + sA)*128 + ic;
      v = fmaxf(Rp0[idx] + Rp1[idx], 0.f);
    }
    Rs[ic][si] = v;
  }
  __syncthreads();

  // up1: 192 thr = (vi3 x oc64), 6 positions each
  {
    const int vi = tid >> 6, oc = tid & 63;
    const float4* w4 = (const float4*)wup1;
    float a[6];
    float bb = bup1[oc];
    #pragma unroll
    for (int p = 0; p < 6; ++p) a[p] = bb;
    #pragma unroll 4
    for (int ic = 0; ic < 128; ++ic) {
      float4 w = w4[(vi*128 + ic)*64 + oc];
      float4 ra = *(const float4*)&Rs[ic][0];
      float4 rb = *(const float4*)&Rs[ic][4];
      float r[8] = {ra.x,ra.y,ra.z,ra.w, rb.x,rb.y,rb.z,rb.w};
      #pragma unroll
      for (int p = 0; p < 6; ++p)
        a[p] = fmaf(r[p],w.x, fmaf(r[p+1],w.y, fmaf(r[p+2],w.z, a[p])));
    }
    #pragma unroll
    for (int p = 0; p < 6; ++p) {
      int sA = s0 - 1 + p;
      u1s[vi][oc][p] = (sA >= 0 && sA < 256) ? fmaxf(a[p], 0.f) : 0.f;
    }
    u1s[vi][oc][6] = 0.f; u1s[vi][oc][7] = 0.f;
  }
  __syncthreads();

  // up2: 160 thr = (v5 x oc32), 4 positions each
  if (tid < 160) {
    const int v = tid >> 5, oc = tid & 31;
    const float4* w4 = (const float4*)wup2;
    float a[4];
    float bb = bup2[oc];
    #pragma unroll
    for (int p = 0; p < 4; ++p) a[p] = bb;
    for (int src = 0; src < 3; ++src) {
      #pragma unroll 4
      for (int ic = 0; ic < 64; ++ic) {
        float4 w = w4[((v*3 + src)*64 + ic)*32 + oc];
        float4 ua = *(const float4*)&u1s[src][ic][0];
        float2 ub = *(const float2*)&u1s[src][ic][4];
        float r[6] = {ua.x,ua.y,ua.z,ua.w, ub.x,ub.y};
        #pragma unroll
        for (int p = 0; p < 4; ++p)
          a[p] = fmaf(r[p],w.x, fmaf(r[p+1],w.y, fmaf(r[p+2],w.z, a[p])));
      }
    }
    #pragma unroll
    for (int p = 0; p < 4; ++p) u2s[v][oc][p] = fmaxf(a[p], 0.f);
  }
  __syncthreads();

  if (tid < 20) {
    int v = tid >> 2, j = tid & 3;
    float a = up3_b[0];
    for (int ic = 0; ic < 32; ++ic)
      a = fmaf(u2s[v][ic][j], up3_w[ic], a);
    H[(size_t)(b*5 + v)*256 + s0 + j] = 1.f / (1.f + expf(-a));
  }
}

// --------------------- range/Doppler spectral + magnitude + final -----------
// 512 blocks (16b x 32 rtiles of 8 r), 256 thr -> 2 blocks/CU = 8 waves.
__global__ __launch_bounds__(256) void k_spec(
    const float* __restrict__ H, const float* __restrict__ wr, const float* __restrict__ wd,
    const float* __restrict__ S01, float* __restrict__ out)
{
  __shared__ float hs[5][256];
  __shared__ float S0[64], S1[64];
  __shared__ float wds[4][64][2];
  __shared__ float ps[32][8][10];
  __shared__ float rred[8][10];
  const int tid = threadIdx.x;
  const int b = blockIdx.x >> 5;
  const int rt = blockIdx.x & 31;
  const int r0 = rt * 8;

  for (int i = tid; i < 1280; i += 256) hs[i >> 8][i & 255] = H[(size_t)b*1280 + i];
  if (tid < 128) {
    int comp = tid >> 6, d = tid & 63;
    float v = S01[comp*64 + d];
    if (comp) S1[d] = v; else S0[d] = v;
  }
  for (int i = tid; i < 512; i += 256) {
    int row = i >> 7, rem = i & 127, d = rem >> 1, comp = rem & 1;
    int c = (row < 2) ? row : (60 + row);
    wds[row][d][comp] = wd[(c*64 + d)*2 + comp];
  }
  __syncthreads();

  {
    const int rl = tid & 7;
    const int sq = tid >> 3;
    const int r = r0 + rl;
    float rr[5] = {0,0,0,0,0}, ri[5] = {0,0,0,0,0};
    const float2* wr2p = (const float2*)wr;
    for (int s = sq*8; s < sq*8 + 8; ++s) {
      float2 w = wr2p[s*256 + r];
      #pragma unroll
      for (int k = 0; k < 5; ++k) {
        float hv = hs[k][s];
        rr[k] = fmaf(hv, w.x, rr[k]);
        ri[k] = fmaf(hv, w.y, ri[k]);
      }
    }
    #pragma unroll
    for (int k = 0; k < 5; ++k) {
      ps[sq][rl][k]     = rr[k];
      ps[sq][rl][5 + k] = ri[k];
    }
  }
  __syncthreads();

  if (tid < 80) {
    const int rl = tid & 7, k = tid >> 3;
    float a = 0.f;
    #pragma unroll
    for (int sq = 0; sq < 32; ++sq) a += ps[sq][rl][k];
    rred[rl][k] = a;
  }
  __syncthreads();

  {
    const int rl = tid & 7, dg = tid >> 3;
    const int r = r0 + rl;
    float Rr[5], Ri[5];
    #pragma unroll
    for (int k = 0; k < 5; ++k) { Rr[k] = rred[rl][k]; Ri[k] = rred[rl][5 + k]; }
    for (int dd = 0; dd < 2; ++dd) {
      int d = dg*2 + dd;
      float w0r = wds[0][d][0], w0i = wds[0][d][1];
      float w1r = wds[1][d][0], w1i = wds[1][d][1];
      float w2r = wds[2][d][0], w2i = wds[2][d][1];
      float w3r = wds[3][d][0], w3i = wds[3][d][1];
      float s0v = S0[d], s1v = S1[d];
      float rdr = Rr[0]*w0r + Rr[1]*w1r + Rr[2]*s0v + Rr[3]*w2r + Rr[4]*w3r
                - Ri[0]*w0i - Ri[1]*w1i - Ri[2]*s1v - Ri[3]*w2i - Ri[4]*w3i;
      float rdi = Rr[0]*w0i + Rr[1]*w1i + Rr[2]*s1v + Rr[3]*w2i + Rr[4]*w3i
                + Ri[0]*w0r + Ri[1]*w1r + Ri[2]*s0v + Ri[3]*w2r + Ri[4]*w3r;
      float mag = sqrtf(rdr*rdr + rdi*rdi) * (1.0f / 16384.0f);
      int v = (d == 0) ? 0 : (d == 1) ? 1 : (d <= 61) ? 2 : ((d == 62) ? 3 : 4);
      float o = hs[v][r] + 0.1f * mag;
      out[(size_t)b*16384 + d*256 + r] = fminf(fmaxf(o, 0.f), 1.f);
    }
  }
}

extern "C" void kernel_launch(void* const* d_in, const int* in_sizes, int n_in,
                              void* d_out, int out_size, void* d_ws, size_t ws_size,
                              hipStream_t stream)
{
  const float* x     = (const float*)d_in[0];
  const float* tc1_w = (const float*)d_in[1];  const float* tc1_b = (const float*)d_in[2];
  const float* tc1_s = (const float*)d_in[3];  const float* tc1_t = (const float*)d_in[4];
  const float* tc2_w = (const float*)d_in[5];  const float* tc2_b = (const float*)d_in[6];
  const float* tc2_s = (const float*)d_in[7];  const float* tc2_t = (const float*)d_in[8];
  const float* rx_w  = (const float*)d_in[9];  const float* rx_b  = (const float*)d_in[10];
  const float* rx_s  = (const float*)d_in[11]; const float* rx_t  = (const float*)d_in[12];
  const float* cc1_w = (const float*)d_in[13]; const float* cc1_b = (const float*)d_in[14];
  const float* cc1_s = (const float*)d_in[15]; const float* cc1_t = (const float*)d_in[16];
  const float* cc2_w = (const float*)d_in[17]; const float* cc2_b = (const float*)d_in[18];
  const float* cc2_s = (const float*)d_in[19]; const float* cc2_t = (const float*)d_in[20];
  const float* rd1_w = (const float*)d_in[21]; const float* rd1_b = (const float*)d_in[22];
  const float* rd1_s = (const float*)d_in[23]; const float* rd1_t = (const float*)d_in[24];
  const float* rd2_w = (const float*)d_in[25]; const float* rd2_b = (const float*)d_in[26];
  const float* rd2_s = (const float*)d_in[27]; const float* rd2_t = (const float*)d_in[28];
  const float* up1_w = (const float*)d_in[29]; const float* up1_b = (const float*)d_in[30];
  const float* up1_s = (const float*)d_in[31]; const float* up1_t = (const float*)d_in[32];
  const float* up2_w = (const float*)d_in[33]; const float* up2_b = (const float*)d_in[34];
  const float* up2_s = (const float*)d_in[35]; const float* up2_t = (const float*)d_in[36];
  const float* up3_w = (const float*)d_in[37]; const float* up3_b = (const float*)d_in[38];
  const float* wr    = (const float*)d_in[39];
  const float* wd    = (const float*)d_in[40];
  float* ws  = (float*)d_ws;
  float* out = (float*)d_out;

  k_repack_front<<<8, 256, 0, stream>>>(tc1_w, tc1_b, tc1_s, tc1_t,
                                        tc2_w, tc2_b, tc2_s, tc2_t,
                                        rx_w, rx_b, rx_s, rx_t, wd, ws);
  k_front<<<1088, 256, 0, stream>>>(x, ws, ws,
                                    cc1_w, cc1_b, cc1_s, cc1_t,
                                    cc2_w, cc2_b, cc2_s, cc2_t,
                                    rd1_w, rd1_b, rd1_s, rd1_t,
                                    rd2_w, rd2_b, rd2_s, rd2_t,
                                    up1_w, up1_b, up1_s, up1_t,
                                    up2_w, up2_b, up2_s, up2_t,
                                    ws + OFF_A);
  k_cc1<<<2048, 256, 0, stream>>>(ws + OFF_A, ws + OFF_WCC1, ws + OFF_P);
  k_mid<<<1024, 256, 0, stream>>>(ws + OFF_P, ws + OFF_BCC1,
                                  ws + OFF_WCC2, ws + OFF_BCC2,
                                  ws + OFF_WRD1, ws + OFF_BRD1,
                                  ws + OFF_WRD2, ws + OFF_BRD2,
                                  ws + OFF_RP0, ws + OFF_RP1);
  k_up<<<1024, 192, 0, stream>>>(ws + OFF_RP0, ws + OFF_RP1,
                                 ws + OFF_WUP1, ws + OFF_BUP1,
                                 ws + OFF_WUP2, ws + OFF_BUP2,
                                 up3_w, up3_b, ws + OFF_H);
  k_spec<<<512, 256, 0, stream>>>(ws + OFF_H, wr, wd, ws + OFF_S01, out);
}

// Round 13
// 337.490 us; speedup vs baseline: 1.1335x; 1.1335x over previous
//
#include <hip/hip_runtime.h>
#include <math.h>

// Workspace float offsets
#define OFF_A      0u          // A (16,2048,256) fp32          8388608
#define OFF_P      8388608u    // cc1 partials [8][16][256][64] 2097152
#define OFF_WCC1   10485760u   // [c2048][oc64][4]               524288
#define OFF_BCC1   11010048u   // 64
#define OFF_WCC2   11010112u   // [ic64][oc64][4]                 16384
#define OFF_BCC2   11026496u   // 64
#define OFF_WRD1   11026560u   // [ic64][oc128][4]                32768
#define OFF_BRD1   11059328u   // 128
#define OFF_WRD2   11059456u   // [ic128][oc128][4]               65536
#define OFF_BRD2   11124992u   // 128
#define OFF_WUP1   11125120u   // [v3][ic128][oc64][4]            98304
#define OFF_BUP1   11223424u   // 64
#define OFF_WUP2   11223488u   // [v5][src3][ic64][oc32][4]      122880
#define OFF_BUP2   11346368u   // 32
#define OFF_WRX    11346400u   // folded rx weights [rxi][ic32][oc32] 4096
#define OFF_W1F    11350496u   // folded tc1 [oc16][6]                96
#define OFF_B1F    11350592u   // 16
#define OFF_W2F    11350608u   // folded tc2 [ic16][k3][oc32]       1536
#define OFF_B2F    11352144u   // 32
#define OFF_BRXF   11352176u   // 32
#define OFF_S01    11352208u   // wd column sums c=2..61 [2][64]     128
// Aliased over A (A dead after k_cc1):
#define OFF_RP0    0u          // rd2 partial half0 [16][256][128] 524288
#define OFF_RP1    524288u     // rd2 partial half1                524288
#define OFF_H      1048576u    // H [16][5][256]                    20480
// total ws floats 11352336 (~43.3 MiB)

__device__ __forceinline__ void fma4(float4& a, const float4& x, float w) {
  a.x = fmaf(x.x, w, a.x); a.y = fmaf(x.y, w, a.y);
  a.z = fmaf(x.z, w, a.z); a.w = fmaf(x.w, w, a.w);
}

// ------------------------------------------- tiny front-weight repack -------
__global__ __launch_bounds__(256) void k_repack_front(
    const float* __restrict__ tc1_w, const float* __restrict__ tc1_b, const float* __restrict__ tc1_s, const float* __restrict__ tc1_t,
    const float* __restrict__ tc2_w, const float* __restrict__ tc2_b, const float* __restrict__ tc2_s, const float* __restrict__ tc2_t,
    const float* __restrict__ rx_w, const float* __restrict__ rx_b, const float* __restrict__ rx_s, const float* __restrict__ rx_t,
    const float* __restrict__ wd,
    float* __restrict__ ws)
{
  const int tid = blockIdx.x * blockDim.x + threadIdx.x;
  const int nth = gridDim.x * blockDim.x;
  for (int i = tid; i < 96; i += nth) ws[OFF_W1F + i] = tc1_w[i] * tc1_s[i/6];
  for (int i = tid; i < 16; i += nth) ws[OFF_B1F + i] = tc1_b[i]*tc1_s[i] + tc1_t[i];
  for (int i = tid; i < 1536; i += nth) {
    int oc = i & 31, r = i >> 5, k = r % 3, ic = r / 3;
    ws[OFF_W2F + i] = tc2_w[oc*48 + ic*3 + k] * tc2_s[oc];
  }
  for (int i = tid; i < 32; i += nth) ws[OFF_B2F + i] = tc2_b[i]*tc2_s[i] + tc2_t[i];
  for (int i = tid; i < 4096; i += nth) {
    int oc = i & 31, ic = (i >> 5) & 31, rxi = i >> 10;
    ws[OFF_WRX + i] = rx_w[(oc*32 + ic)*4 + rxi] * rx_s[oc];
  }
  for (int i = tid; i < 32; i += nth) ws[OFF_BRXF + i] = rx_b[i]*rx_s[i] + rx_t[i];
  for (int i = tid; i < 128; i += nth) {
    int d = i & 63, comp = i >> 6;
    float a = 0.f;
    for (int c = 2; c <= 61; ++c) a += wd[(c*64 + d)*2 + comp];
    ws[OFF_S01 + comp*64 + d] = a;
  }
}

// ---------------------- fused tc1+tc2+rx  +  heavy weight repack ------------
__global__ __launch_bounds__(256, 4) void k_front(
    const float* __restrict__ x, const float* __restrict__ ws_c, float* __restrict__ ws,
    const float* __restrict__ cc1_w, const float* __restrict__ cc1_b, const float* __restrict__ cc1_s, const float* __restrict__ cc1_t,
    const float* __restrict__ cc2_w, const float* __restrict__ cc2_b, const float* __restrict__ cc2_s, const float* __restrict__ cc2_t,
    const float* __restrict__ rd1_w, const float* __restrict__ rd1_b, const float* __restrict__ rd1_s, const float* __restrict__ rd1_t,
    const float* __restrict__ rd2_w, const float* __restrict__ rd2_b, const float* __restrict__ rd2_s, const float* __restrict__ rd2_t,
    const float* __restrict__ up1_w, const float* __restrict__ up1_b, const float* __restrict__ up1_s, const float* __restrict__ up1_t,
    const float* __restrict__ up2_w, const float* __restrict__ up2_b, const float* __restrict__ up2_s, const float* __restrict__ up2_t,
    float* __restrict__ A)
{
  __shared__ float t1s[16][258];
  const int tid = threadIdx.x;

  if (blockIdx.x < 64) {
    const int t = blockIdx.x * 256 + tid;
    const int nth = 64 * 256;
    for (int i = t; i < 2048*64*4; i += nth) {
      int k = i & 3, oc = (i >> 2) & 63, c2 = i >> 8;
      ws[OFF_WCC1 + i] = (k < 3) ? cc1_w[((oc*2048 + c2)*3 + 1)*3 + k] * cc1_s[oc] : 0.f;
    }
    for (int i = t; i < 64; i += nth) ws[OFF_BCC1 + i] = cc1_b[i]*cc1_s[i] + cc1_t[i];
    for (int i = t; i < 64*64; i += nth) {
      int oc = i & 63, ic = i >> 6;
      float4 v;
      v.x = cc2_w[(oc*64 + ic)*9 + 3] * cc2_s[oc];
      v.y = cc2_w[(oc*64 + ic)*9 + 4] * cc2_s[oc];
      v.z = cc2_w[(oc*64 + ic)*9 + 5] * cc2_s[oc];
      v.w = 0.f;
      ((float4*)(ws + OFF_WCC2))[i] = v;
    }
    for (int i = t; i < 64; i += nth) ws[OFF_BCC2 + i] = cc2_b[i]*cc2_s[i] + cc2_t[i];
    for (int i = t; i < 64*128; i += nth) {
      int oc = i & 127, ic = i >> 7;
      float4 v;
      v.x = rd1_w[(oc*64 + ic)*9 + 3] * rd1_s[oc];
      v.y = rd1_w[(oc*64 + ic)*9 + 4] * rd1_s[oc];
      v.z = rd1_w[(oc*64 + ic)*9 + 5] * rd1_s[oc];
      v.w = 0.f;
      ((float4*)(ws + OFF_WRD1))[i] = v;
    }
    for (int i = t; i < 128; i += nth) ws[OFF_BRD1 + i] = rd1_b[i]*rd1_s[i] + rd1_t[i];
    for (int i = t; i < 128*128; i += nth) {
      int oc = i & 127, ic = i >> 7;
      float4 v;
      v.x = rd2_w[(oc*128 + ic)*9 + 3] * rd2_s[oc];
      v.y = rd2_w[(oc*128 + ic)*9 + 4] * rd2_s[oc];
      v.z = rd2_w[(oc*128 + ic)*9 + 5] * rd2_s[oc];
      v.w = 0.f;
      ((float4*)(ws + OFF_WRD2))[i] = v;
    }
    for (int i = t; i < 128; i += nth) ws[OFF_BRD2 + i] = rd2_b[i]*rd2_s[i] + rd2_t[i];
    for (int i = t; i < 3*128*64; i += nth) {
      int oc = i & 63, ic = (i >> 6) & 127, v = i >> 13;
      const int m = (v == 0) ? 6 : (v == 1) ? 7 : 3;
      float4 o = make_float4(0.f, 0.f, 0.f, 0.f);
      for (int kh = 0; kh < 3; ++kh)
        if ((m >> kh) & 1) {
          o.x += up1_w[((oc*128 + ic)*3 + kh)*3 + 0];
          o.y += up1_w[((oc*128 + ic)*3 + kh)*3 + 1];
          o.z += up1_w[((oc*128 + ic)*3 + kh)*3 + 2];
        }
      o.x *= up1_s[oc]; o.y *= up1_s[oc]; o.z *= up1_s[oc];
      ((float4*)(ws + OFF_WUP1))[i] = o;
    }
    for (int i = t; i < 64; i += nth) ws[OFF_BUP1 + i] = up1_b[i]*up1_s[i] + up1_t[i];
    for (int i = t; i < 5*3*64*32; i += nth) {
      int oc = i & 31, ic = (i >> 5) & 63, tt = i >> 11;
      int src = tt % 3, v = tt / 3;
      const int MASKS[15] = {2,4,0,  1,6,0,  0,7,0,  0,3,4,  0,1,2};
      const int m = MASKS[v*3 + src];
      float4 o = make_float4(0.f, 0.f, 0.f, 0.f);
      for (int kh = 0; kh < 3; ++kh)
        if ((m >> kh) & 1) {
          o.x += up2_w[((oc*64 + ic)*3 + kh)*3 + 0];
          o.y += up2_w[((oc*64 + ic)*3 + kh)*3 + 1];
          o.z += up2_w[((oc*64 + ic)*3 + kh)*3 + 2];
        }
      o.x *= up2_s[oc]; o.y *= up2_s[oc]; o.z *= up2_s[oc];
      ((float4*)(ws + OFF_WUP2))[i] = o;
    }
    for (int i = t; i < 32; i += nth) ws[OFF_BUP2 + i] = up2_b[i]*up2_s[i] + up2_t[i];
    return;
  }

  // ---------------------------- front compute -------------------------------
  const int bb = blockIdx.x - 64;
  const int b = bb >> 6, chirp = bb & 63;
  const int s = tid;

  if (tid < 32) { int o = tid & 15; int c = (tid >> 4) ? 257 : 0; t1s[o][c] = 0.f; }

  const float* w1f  = ws_c + OFF_W1F;
  const float* b1f  = ws_c + OFF_B1F;
  const float* w2f  = ws_c + OFF_W2F;
  const float* b2f  = ws_c + OFF_B2F;
  const float* wrxf = ws_c + OFF_WRX;
  const float* brxf = ws_c + OFF_BRXF;

  float acc[32];
  #pragma unroll
  for (int j = 0; j < 32; ++j) acc[j] = 0.f;

  #pragma unroll 1
  for (int rxi = 0; rxi < 4; ++rxi) {
    {
      const float2* xb2 = (const float2*)(x + ((size_t)(((b*4 + rxi)*64 + chirp)*256) << 1));
      float2 xm = xb2[s];
      float2 xl = xb2[(s == 0) ? 0 : (s - 1)];
      float2 xr = xb2[(s == 255) ? 255 : (s + 1)];
      if (s == 0)   { xl.x = 0.f; xl.y = 0.f; }
      if (s == 255) { xr.x = 0.f; xr.y = 0.f; }
      #pragma unroll 4
      for (int o = 0; o < 16; ++o) {
        const float* w = w1f + o*6;
        float v = b1f[o];
        v = fmaf(xl.x, w[0], v);
        v = fmaf(xm.x, w[1], v);
        v = fmaf(xr.x, w[2], v);
        v = fmaf(xl.y, w[3], v);
        v = fmaf(xm.y, w[4], v);
        v = fmaf(xr.y, w[5], v);
        t1s[o][s+1] = fmaxf(v, 0.f);
      }
    }
    __syncthreads();

    float t2[32];
    #pragma unroll
    for (int j = 0; j < 32; ++j) t2[j] = b2f[j];
    #pragma unroll 2
    for (int ic = 0; ic < 16; ++ic) {
      float tl = t1s[ic][s];
      float tm = t1s[ic][s+1];
      float tr = t1s[ic][s+2];
      const float* w = w2f + ic*96;
      #pragma unroll
      for (int oc = 0; oc < 32; ++oc)
        t2[oc] = fmaf(tl, w[oc], fmaf(tm, w[32+oc], fmaf(tr, w[64+oc], t2[oc])));
    }
    #pragma unroll
    for (int j = 0; j < 32; ++j) t2[j] = fmaxf(t2[j], 0.f);

    const float* wr0 = wrxf + rxi*1024;
    #pragma unroll 4
    for (int ic = 0; ic < 32; ++ic) {
      float tv = t2[ic];
      const float* w = wr0 + ic*32;
      #pragma unroll
      for (int oc = 0; oc < 32; ++oc)
        acc[oc] = fmaf(tv, w[oc], acc[oc]);
    }
    __syncthreads();
  }

  #pragma unroll 4
  for (int oc = 0; oc < 32; ++oc) {
    float v = fmaxf(acc[oc] + brxf[oc], 0.f);
    A[(size_t)((b*2048 + oc*64 + chirp)*256) + s] = v;
  }
}

// --------------------------------------------------------- cc1 (split-K8) ---
// R8-measured shape: 1024 blocks (16b x 8st(32) x 8ks), 256 thr = (oc64 x sg4),
// 8 samples/thread. Per c: 1 coalesced VMEM float4 + 3 broadcast LDS + 24 FMA.
// LDS 36.8 KB -> 4 blocks/CU = 16 waves/CU.
__global__ __launch_bounds__(256) void k_cc1(
    const float* __restrict__ A, const float* __restrict__ wp, float* __restrict__ P)
{
  __shared__ __align__(16) float As[256][36];
  const int tid = threadIdx.x;
  const int ks = blockIdx.x & 7;
  const int stile = (blockIdx.x >> 3) & 7;
  const int b = blockIdx.x >> 6;
  const int s0 = stile * 32;
  const int oc = tid & 63;
  const int sg = tid >> 6;
  const int cbase = ks * 256;
  const float4* w4 = (const float4*)wp;

  for (int i = tid; i < 256*36; i += 256) {
    int c = i / 36, si = i - c*36;
    int sA = s0 - 1 + si;
    float v = 0.f;
    if (si < 34 && sA >= 0 && sA < 256)
      v = A[(size_t)(b*2048 + cbase + c)*256 + sA];
    As[c][si] = v;
  }
  __syncthreads();

  const int sb = sg * 8;
  float4 acc0 = make_float4(0.f,0.f,0.f,0.f);
  float4 acc1 = make_float4(0.f,0.f,0.f,0.f);
  #pragma unroll 4
  for (int c = 0; c < 256; ++c) {
    float4 w = w4[(size_t)(cbase + c)*64 + oc];
    float4 a0 = *(const float4*)&As[c][sb];
    float4 a1 = *(const float4*)&As[c][sb + 4];
    float2 a2 = *(const float2*)&As[c][sb + 8];
    acc0.x = fmaf(a0.x,w.x, fmaf(a0.y,w.y, fmaf(a0.z,w.z, acc0.x)));
    acc0.y = fmaf(a0.y,w.x, fmaf(a0.z,w.y, fmaf(a0.w,w.z, acc0.y)));
    acc0.z = fmaf(a0.z,w.x, fmaf(a0.w,w.y, fmaf(a1.x,w.z, acc0.z)));
    acc0.w = fmaf(a0.w,w.x, fmaf(a1.x,w.y, fmaf(a1.y,w.z, acc0.w)));
    acc1.x = fmaf(a1.x,w.x, fmaf(a1.y,w.y, fmaf(a1.z,w.z, acc1.x)));
    acc1.y = fmaf(a1.y,w.x, fmaf(a1.z,w.y, fmaf(a1.w,w.z, acc1.y)));
    acc1.z = fmaf(a1.z,w.x, fmaf(a1.w,w.y, fmaf(a2.x,w.z, acc1.z)));
    acc1.w = fmaf(a1.w,w.x, fmaf(a2.x,w.y, fmaf(a2.y,w.z, acc1.w)));
  }
  float* Pk = P + ((size_t)(ks*16 + b)*256)*64;
  int s = s0 + sb;
  Pk[(size_t)(s+0)*64 + oc] = acc0.x;
  Pk[(size_t)(s+1)*64 + oc] = acc0.y;
  Pk[(size_t)(s+2)*64 + oc] = acc0.z;
  Pk[(size_t)(s+3)*64 + oc] = acc0.w;
  Pk[(size_t)(s+4)*64 + oc] = acc1.x;
  Pk[(size_t)(s+5)*64 + oc] = acc1.y;
  Pk[(size_t)(s+6)*64 + oc] = acc1.z;
  Pk[(size_t)(s+7)*64 + oc] = acc1.w;
}

// ------------------- fused cc2 + rd1 + rd2 (oc-half split) ------------------
__global__ __launch_bounds__(256) void k_mid(
    const float* __restrict__ P, const float* __restrict__ bcc1,
    const float* __restrict__ wcc2, const float* __restrict__ bcc2,
    const float* __restrict__ wrd1, const float* __restrict__ brd1,
    const float* __restrict__ wrd2, const float* __restrict__ brd2,
    float* __restrict__ Rp0, float* __restrict__ Rp1)
{
  __shared__ __align__(16) float c1s[64][20];
  __shared__ __align__(16) float c2s[64][20];
  __shared__ __align__(16) float r1s[64][12];
  const int tid = threadIdx.x;
  const int half = blockIdx.x & 1;
  const int stile = (blockIdx.x >> 1) & 31;
  const int b = blockIdx.x >> 6;
  const int s0 = stile * 8;
  const float4* wc2 = (const float4*)wcc2;
  const float4* wr1 = (const float4*)wrd1;
  const float4* wr2 = (const float4*)wrd2;

  for (int i = tid; i < 14*64; i += 256) {
    int ic = i & 63, si = i >> 6;
    int sA = s0 - 3 + si;
    float v = 0.f;
    if (sA >= 0 && sA < 256) {
      float a = bcc1[ic];
      #pragma unroll
      for (int ksp = 0; ksp < 8; ++ksp)
        a += P[((size_t)(ksp*16 + b)*256 + sA)*64 + ic];
      v = fmaxf(a, 0.f);
    }
    c1s[ic][si] = v;
  }
  __syncthreads();

  {
    const int g = tid >> 6, oc = tid & 63;
    if (g < 3) {
      float bb = bcc2[oc];
      float4 acc = make_float4(bb, bb, bb, bb);
      #pragma unroll 4
      for (int ic = 0; ic < 64; ++ic) {
        float4 w = wc2[ic*64 + oc];
        float4 ca = *(const float4*)&c1s[ic][g*4];
        float2 cb = *(const float2*)&c1s[ic][g*4 + 4];
        acc.x = fmaf(ca.x,w.x, fmaf(ca.y,w.y, fmaf(ca.z,w.z, acc.x)));
        acc.y = fmaf(ca.y,w.x, fmaf(ca.z,w.y, fmaf(ca.w,w.z, acc.y)));
        acc.z = fmaf(ca.z,w.x, fmaf(ca.w,w.y, fmaf(cb.x,w.z, acc.z)));
        acc.w = fmaf(ca.w,w.x, fmaf(cb.x,w.y, fmaf(cb.y,w.z, acc.w)));
      }
      float r[4] = {acc.x, acc.y, acc.z, acc.w};
      #pragma unroll
      for (int j = 0; j < 4; ++j) {
        int si = g*4 + j, sA = s0 - 2 + si;
        c2s[oc][si] = (sA >= 0 && sA < 256) ? fmaxf(r[j], 0.f) : 0.f;
      }
    } else {
      int oc2 = tid - 192;
      c2s[oc2][12] = 0.f;
      c2s[oc2][13] = 0.f;
    }
  }
  __syncthreads();

  {
    const int g = tid >> 6, ocl = tid & 63;
    if (g < 3) {
      const int ocg = half*64 + ocl;
      float bb = brd1[ocg];
      float4 acc = make_float4(bb, bb, bb, bb);
      #pragma unroll 4
      for (int ic = 0; ic < 64; ++ic) {
        float4 w = wr1[ic*128 + ocg];
        float4 ca = *(const float4*)&c2s[ic][g*4];
        float2 cb = *(const float2*)&c2s[ic][g*4 + 4];
        acc.x = fmaf(ca.x,w.x, fmaf(ca.y,w.y, fmaf(ca.z,w.z, acc.x)));
        acc.y = fmaf(ca.y,w.x, fmaf(ca.z,w.y, fmaf(ca.w,w.z, acc.y)));
        acc.z = fmaf(ca.z,w.x, fmaf(ca.w,w.y, fmaf(cb.x,w.z, acc.z)));
        acc.w = fmaf(ca.w,w.x, fmaf(cb.x,w.y, fmaf(cb.y,w.z, acc.w)));
      }
      float r[4] = {acc.x, acc.y, acc.z, acc.w};
      #pragma unroll
      for (int j = 0; j < 4; ++j) {
        int si = g*4 + j, sA = s0 - 1 + si;
        if (si < 10)
          r1s[ocl][si] = (sA >= 0 && sA < 256) ? fmaxf(r[j], 0.f) : 0.f;
      }
    } else {
      int oc2 = tid - 192;
      r1s[oc2][10] = 0.f;
      r1s[oc2][11] = 0.f;
    }
  }
  __syncthreads();

  {
    const int g = tid >> 7, oc = tid & 127;
    float bb = half ? 0.f : brd2[oc];
    float4 acc = make_float4(bb, bb, bb, bb);
    #pragma unroll 4
    for (int ic = 0; ic < 64; ++ic) {
      float4 w = wr2[(half*64 + ic)*128 + oc];
      float4 ca = *(const float4*)&r1s[ic][g*4];
      float2 cb = *(const float2*)&r1s[ic][g*4 + 4];
      acc.x = fmaf(ca.x,w.x, fmaf(ca.y,w.y, fmaf(ca.z,w.z, acc.x)));
      acc.y = fmaf(ca.y,w.x, fmaf(ca.z,w.y, fmaf(ca.w,w.z, acc.y)));
      acc.z = fmaf(ca.z,w.x, fmaf(ca.w,w.y, fmaf(cb.x,w.z, acc.z)));
      acc.w = fmaf(ca.w,w.x, fmaf(cb.x,w.y, fmaf(cb.y,w.z, acc.w)));
    }
    float* Rp = half ? Rp1 : Rp0;
    int s = s0 + g*4;
    Rp[((size_t)b*256 + s+0)*128 + oc] = acc.x;
    Rp[((size_t)b*256 + s+1)*128 + oc] = acc.y;
    Rp[((size_t)b*256 + s+2)*128 + oc] = acc.z;
    Rp[((size_t)b*256 + s+3)*128 + oc] = acc.w;
  }
}

// ------------------------- fused up1 + up2 + up3 + sigmoid ------------------
// 1024 blocks (16b x 64 tiles of 4 samples), 192 thr.
__global__ __launch_bounds__(192) void k_up(
    const float* __restrict__ Rp0, const float* __restrict__ Rp1,
    const float* __restrict__ wup1, const float* __restrict__ bup1,
    const float* __restrict__ wup2, const float* __restrict__ bup2,
    const float* __restrict__ up3_w, const float* __restrict__ up3_b,
    float* __restrict__ H)
{
  __shared__ __align__(16) float Rs[128][8];
  __shared__ __align__(16) float u1s[3][64][8];
  __shared__ float u2s[5][32][5];
  const int tid = threadIdx.x;
  const int b = blockIdx.x >> 6;
  const int s0 = (blockIdx.x & 63) * 4;

  for (int i = tid; i < 128*8; i += 192) {
    int ic = i >> 3, si = i & 7;
    int sA = s0 - 2 + si;
    float v = 0.f;
    if (sA >= 0 && sA < 256) {
      size_t idx = ((size_t)b*256 + sA)*128 + ic;
      v = fmaxf(Rp0[idx] + Rp1[idx], 0.f);
    }
    Rs[ic][si] = v;
  }
  __syncthreads();

  {
    const int vi = tid >> 6, oc = tid & 63;
    const float4* w4 = (const float4*)wup1;
    float a[6];
    float bb = bup1[oc];
    #pragma unroll
    for (int p = 0; p < 6; ++p) a[p] = bb;
    #pragma unroll 4
    for (int ic = 0; ic < 128; ++ic) {
      float4 w = w4[(vi*128 + ic)*64 + oc];
      float4 ra = *(const float4*)&Rs[ic][0];
      float4 rb = *(const float4*)&Rs[ic][4];
      float r[8] = {ra.x,ra.y,ra.z,ra.w, rb.x,rb.y,rb.z,rb.w};
      #pragma unroll
      for (int p = 0; p < 6; ++p)
        a[p] = fmaf(r[p],w.x, fmaf(r[p+1],w.y, fmaf(r[p+2],w.z, a[p])));
    }
    #pragma unroll
    for (int p = 0; p < 6; ++p) {
      int sA = s0 - 1 + p;
      u1s[vi][oc][p] = (sA >= 0 && sA < 256) ? fmaxf(a[p], 0.f) : 0.f;
    }
    u1s[vi][oc][6] = 0.f; u1s[vi][oc][7] = 0.f;
  }
  __syncthreads();

  if (tid < 160) {
    const int v = tid >> 5, oc = tid & 31;
    const float4* w4 = (const float4*)wup2;
    float a[4];
    float bb = bup2[oc];
    #pragma unroll
    for (int p = 0; p < 4; ++p) a[p] = bb;
    for (int src = 0; src < 3; ++src) {
      #pragma unroll 4
      for (int ic = 0; ic < 64; ++ic) {
        float4 w = w4[((v*3 + src)*64 + ic)*32 + oc];
        float4 ua = *(const float4*)&u1s[src][ic][0];
        float2 ub = *(const float2*)&u1s[src][ic][4];
        float r[6] = {ua.x,ua.y,ua.z,ua.w, ub.x,ub.y};
        #pragma unroll
        for (int p = 0; p < 4; ++p)
          a[p] = fmaf(r[p],w.x, fmaf(r[p+1],w.y, fmaf(r[p+2],w.z, a[p])));
      }
    }
    #pragma unroll
    for (int p = 0; p < 4; ++p) u2s[v][oc][p] = fmaxf(a[p], 0.f);
  }
  __syncthreads();

  if (tid < 20) {
    int v = tid >> 2, j = tid & 3;
    float a = up3_b[0];
    for (int ic = 0; ic < 32; ++ic)
      a = fmaf(u2s[v][ic][j], up3_w[ic], a);
    H[(size_t)(b*5 + v)*256 + s0 + j] = 1.f / (1.f + expf(-a));
  }
}

// --------------------- range/Doppler spectral + magnitude + final -----------
__global__ __launch_bounds__(256) void k_spec(
    const float* __restrict__ H, const float* __restrict__ wr, const float* __restrict__ wd,
    const float* __restrict__ S01, float* __restrict__ out)
{
  __shared__ float hs[5][256];
  __shared__ float S0[64], S1[64];
  __shared__ float wds[4][64][2];
  __shared__ float ps[32][8][10];
  __shared__ float rred[8][10];
  const int tid = threadIdx.x;
  const int b = blockIdx.x >> 5;
  const int rt = blockIdx.x & 31;
  const int r0 = rt * 8;

  for (int i = tid; i < 1280; i += 256) hs[i >> 8][i & 255] = H[(size_t)b*1280 + i];
  if (tid < 128) {
    int comp = tid >> 6, d = tid & 63;
    float v = S01[comp*64 + d];
    if (comp) S1[d] = v; else S0[d] = v;
  }
  for (int i = tid; i < 512; i += 256) {
    int row = i >> 7, rem = i & 127, d = rem >> 1, comp = rem & 1;
    int c = (row < 2) ? row : (60 + row);
    wds[row][d][comp] = wd[(c*64 + d)*2 + comp];
  }
  __syncthreads();

  {
    const int rl = tid & 7;
    const int sq = tid >> 3;
    const int r = r0 + rl;
    float rr[5] = {0,0,0,0,0}, ri[5] = {0,0,0,0,0};
    const float2* wr2p = (const float2*)wr;
    for (int s = sq*8; s < sq*8 + 8; ++s) {
      float2 w = wr2p[s*256 + r];
      #pragma unroll
      for (int k = 0; k < 5; ++k) {
        float hv = hs[k][s];
        rr[k] = fmaf(hv, w.x, rr[k]);
        ri[k] = fmaf(hv, w.y, ri[k]);
      }
    }
    #pragma unroll
    for (int k = 0; k < 5; ++k) {
      ps[sq][rl][k]     = rr[k];
      ps[sq][rl][5 + k] = ri[k];
    }
  }
  __syncthreads();

  if (tid < 80) {
    const int rl = tid & 7, k = tid >> 3;
    float a = 0.f;
    #pragma unroll
    for (int sq = 0; sq < 32; ++sq) a += ps[sq][rl][k];
    rred[rl][k] = a;
  }
  __syncthreads();

  {
    const int rl = tid & 7, dg = tid >> 3;
    const int r = r0 + rl;
    float Rr[5], Ri[5];
    #pragma unroll
    for (int k = 0; k < 5; ++k) { Rr[k] = rred[rl][k]; Ri[k] = rred[rl][5 + k]; }
    for (int dd = 0; dd < 2; ++dd) {
      int d = dg*2 + dd;
      float w0r = wds[0][d][0], w0i = wds[0][d][1];
      float w1r = wds[1][d][0], w1i = wds[1][d][1];
      float w2r = wds[2][d][0], w2i = wds[2][d][1];
      float w3r = wds[3][d][0], w3i = wds[3][d][1];
      float s0v = S0[d], s1v = S1[d];
      float rdr = Rr[0]*w0r + Rr[1]*w1r + Rr[2]*s0v + Rr[3]*w2r + Rr[4]*w3r
                - Ri[0]*w0i - Ri[1]*w1i - Ri[2]*s1v - Ri[3]*w2i - Ri[4]*w3i;
      float rdi = Rr[0]*w0i + Rr[1]*w1i + Rr[2]*s1v + Rr[3]*w2i + Rr[4]*w3i
                + Ri[0]*w0r + Ri[1]*w1r + Ri[2]*s0v + Ri[3]*w2r + Ri[4]*w3r;
      float mag = sqrtf(rdr*rdr + rdi*rdi) * (1.0f / 16384.0f);
      int v = (d == 0) ? 0 : (d == 1) ? 1 : (d <= 61) ? 2 : ((d == 62) ? 3 : 4);
      float o = hs[v][r] + 0.1f * mag;
      out[(size_t)b*16384 + d*256 + r] = fminf(fmaxf(o, 0.f), 1.f);
    }
  }
}

extern "C" void kernel_launch(void* const* d_in, const int* in_sizes, int n_in,
                              void* d_out, int out_size, void* d_ws, size_t ws_size,
                              hipStream_t stream)
{
  const float* x     = (const float*)d_in[0];
  const float* tc1_w = (const float*)d_in[1];  const float* tc1_b = (const float*)d_in[2];
  const float* tc1_s = (const float*)d_in[3];  const float* tc1_t = (const float*)d_in[4];
  const float* tc2_w = (const float*)d_in[5];  const float* tc2_b = (const float*)d_in[6];
  const float* tc2_s = (const float*)d_in[7];  const float* tc2_t = (const float*)d_in[8];
  const float* rx_w  = (const float*)d_in[9];  const float* rx_b  = (const float*)d_in[10];
  const float* rx_s  = (const float*)d_in[11]; const float* rx_t  = (const float*)d_in[12];
  const float* cc1_w = (const float*)d_in[13]; const float* cc1_b = (const float*)d_in[14];
  const float* cc1_s = (const float*)d_in[15]; const float* cc1_t = (const float*)d_in[16];
  const float* cc2_w = (const float*)d_in[17]; const float* cc2_b = (const float*)d_in[18];
  const float* cc2_s = (const float*)d_in[19]; const float* cc2_t = (const float*)d_in[20];
  const float* rd1_w = (const float*)d_in[21]; const float* rd1_b = (const float*)d_in[22];
  const float* rd1_s = (const float*)d_in[23]; const float* rd1_t = (const float*)d_in[24];
  const float* rd2_w = (const float*)d_in[25]; const float* rd2_b = (const float*)d_in[26];
  const float* rd2_s = (const float*)d_in[27]; const float* rd2_t = (const float*)d_in[28];
  const float* up1_w = (const float*)d_in[29]; const float* up1_b = (const float*)d_in[30];
  const float* up1_s = (const float*)d_in[31]; const float* up1_t = (const float*)d_in[32];
  const float* up2_w = (const float*)d_in[33]; const float* up2_b = (const float*)d_in[34];
  const float* up2_s = (const float*)d_in[35]; const float* up2_t = (const float*)d_in[36];
  const float* up3_w = (const float*)d_in[37]; const float* up3_b = (const float*)d_in[38];
  const float* wr    = (const float*)d_in[39];
  const float* wd    = (const float*)d_in[40];
  float* ws  = (float*)d_ws;
  float* out = (float*)d_out;

  k_repack_front<<<8, 256, 0, stream>>>(tc1_w, tc1_b, tc1_s, tc1_t,
                                        tc2_w, tc2_b, tc2_s, tc2_t,
                                        rx_w, rx_b, rx_s, rx_t, wd, ws);
  k_front<<<1088, 256, 0, stream>>>(x, ws, ws,
                                    cc1_w, cc1_b, cc1_s, cc1_t,
                                    cc2_w, cc2_b, cc2_s, cc2_t,
                                    rd1_w, rd1_b, rd1_s, rd1_t,
                                    rd2_w, rd2_b, rd2_s, rd2_t,
                                    up1_w, up1_b, up1_s, up1_t,
                                    up2_w, up2_b, up2_s, up2_t,
                                    ws + OFF_A);
  k_cc1<<<1024, 256, 0, stream>>>(ws + OFF_A, ws + OFF_WCC1, ws + OFF_P);
  k_mid<<<1024, 256, 0, stream>>>(ws + OFF_P, ws + OFF_BCC1,
                                  ws + OFF_WCC2, ws + OFF_BCC2,
                                  ws + OFF_WRD1, ws + OFF_BRD1,
                                  ws + OFF_WRD2, ws + OFF_BRD2,
                                  ws + OFF_RP0, ws + OFF_RP1);
  k_up<<<1024, 192, 0, stream>>>(ws + OFF_RP0, ws + OFF_RP1,
                                 ws + OFF_WUP1, ws + OFF_BUP1,
                                 ws + OFF_WUP2, ws + OFF_BUP2,
                                 up3_w, up3_b, ws + OFF_H);
  k_spec<<<512, 256, 0, stream>>>(ws + OFF_H, wr, wd, ws + OFF_S01, out);
}